// Round 18
// baseline (93.947 us; speedup 1.0000x reference)
//
#include <hip/hip_runtime.h>

typedef unsigned short u16;
typedef unsigned int u32;
typedef __bf16 bf16x8 __attribute__((ext_vector_type(8)));
typedef float f32x4 __attribute__((ext_vector_type(4)));
typedef u16 u16x4 __attribute__((ext_vector_type(4)));
typedef u16 u16x8 __attribute__((ext_vector_type(8)));

#define LSEQ 2048
#define EMB  1024
#define NH   16
#define HDIM 64

// Q pre-scale: 1/sqrt(64) * log2(e)  (softmax computed in base 2)
#define QSCALE 0.1803368808f

#if __has_builtin(__builtin_amdgcn_exp2f)
#define EXP2(x) __builtin_amdgcn_exp2f(x)
#else
#define EXP2(x) __expf((x) * 0.6931471805599453f)
#endif

__device__ __forceinline__ u16 cvt_bf(float f) {
  __bf16 h = (__bf16)f;
  return __builtin_bit_cast(u16, h);
}
__device__ __forceinline__ float bf2f(u16 v) {
  return __uint_as_float(((unsigned)v) << 16);
}
__device__ __forceinline__ void async16(void* lds, const void* g) {
  __builtin_amdgcn_global_load_lds((const __attribute__((address_space(1))) void*)g,
                                   (__attribute__((address_space(3))) void*)lds, 16, 0, 0);
}
__device__ __forceinline__ f32x4 mfma16(bf16x8 a, bf16x8 b, f32x4 c) {
  return __builtin_amdgcn_mfma_f32_16x16x32_bf16(a, b, c, 0, 0, 0);
}

// ---------------- fused prep: x conversion + both weight transposes (R14) ----------------
__global__ void prep(const float* __restrict__ x, u16* __restrict__ xb,
                     const float* __restrict__ Wqkv, u16* __restrict__ WqkvT,
                     const float* __restrict__ Wo, u16* __restrict__ WoT) {
  __shared__ float tile[32][33];
  const int bid = blockIdx.x;
  const int tid = threadIdx.x;
  if (bid < 2048) {
    const int n4 = 1024 * 1024;
    for (int i = bid * 256 + tid; i < n4; i += 2048 * 256) {
      float4 v = ((const float4*)x)[i];
      u16x4 o = { cvt_bf(v.x), cvt_bf(v.y), cvt_bf(v.z), cvt_bf(v.w) };
      ((u16x4*)xb)[i] = o;
    }
    return;
  }
  const int idx = bid - 2048;          // 0..4095
  const int bx = idx & 127, by = idx >> 7;
  const int Kd = 1024;
  const float* in;
  u16* out;
  int Nd, n0;
  if (bx < 96) { in = Wqkv; out = WqkvT; Nd = 3072; n0 = bx * 32; }
  else         { in = Wo;   out = WoT;   Nd = 1024; n0 = (bx - 96) * 32; }
  const int k0 = by * 32;
  const int tx = tid & 31, ty = tid >> 5;   // (32,8)
#pragma unroll
  for (int i = 0; i < 4; ++i)
    tile[ty + i * 8][tx] = in[(size_t)(k0 + ty + i * 8) * Nd + n0 + tx];
  __syncthreads();
#pragma unroll
  for (int i = 0; i < 4; ++i)
    out[(size_t)(n0 + ty + i * 8) * Kd + k0 + tx] = cvt_bf(tile[tx][ty + i * 8]);
}

// ---------------- QKV GEMM, R18: BN=64 typed blocks -> 48KB LDS, 3 blocks/CU ----------------
// Same verified BK=64 + XOR-16 template as R14; parameter change only:
// each block = ONE (head, type) 64-col window, BM=128. Grid 1536 (48 typed
// n-blocks x 32 m-tiles) smooths mask-skip raggedness; occupancy 8->12
// waves/CU. Staging 6 calls/tile -> vmcnt(6). Per-wave acc[4][2].
__launch_bounds__(256, 3)
__global__ void gemm_qkv(const u16* __restrict__ A, const u16* __restrict__ Bt,
                         const float* __restrict__ bias,
                         u16* __restrict__ Qo, u16* __restrict__ Ko, u16* __restrict__ Vo,
                         const int* __restrict__ mask_len) {
  __shared__ __attribute__((aligned(16))) u16 SMEM[2 * 8192 + 2 * 4096];  // As[2][128*64] Bs[2][64*64]
  u16* As = SMEM;
  u16* Bs = SMEM + 2 * 8192;
  const int tid = threadIdx.x;
  const int w = tid >> 6, l = tid & 63;
  const int g = l >> 4, cc = l & 15;
  const int orig = blockIdx.y * 48 + blockIdx.x;
  const int wgid = (orig & 7) * 192 + (orig >> 3);  // XCD-bijective (1536 % 8 == 0)
  const int m0 = (wgid / 48) * 128;
  const int tb = wgid % 48;
  const int type = tb >> 4, head = tb & 15;         // 0=Q 1=K 2=V; single head
  const int bb = m0 >> 11;
  const int lo = mask_len[bb];
  if (type < 2 && (m0 & (LSEQ - 1)) >= lo) return;  // dead Q/K rows
  const int wm = w >> 1, wn = w & 1;
  const int K = 1024;

  const int srow8 = tid >> 3;       // 0..31 row within call
  const int chunk = tid & 7;
  auto stage = [&](int buf, int k0) {
#pragma unroll
    for (int c = 0; c < 4; ++c) {
      int R = c * 32 + srow8;                 // 0..127 A-panel row
      int col = (chunk ^ (R & 7)) * 8;        // pre-swizzled source (elems)
      async16((char*)&As[buf * 8192] + c * 4096 + w * 1024,
              A + (size_t)(m0 + R) * K + k0 + col);
    }
#pragma unroll
    for (int c = 0; c < 2; ++c) {
      int R = c * 32 + srow8;                 // 0..63 B-panel row
      int col = (chunk ^ (R & 7)) * 8;
      int gR = head * 192 + type * 64 + R;
      async16((char*)&Bs[buf * 4096] + c * 4096 + w * 1024,
              Bt + (size_t)gR * K + k0 + col);
    }
  };

  f32x4 acc[4][2] = {};
  stage(0, 0);
  for (int t = 0; t < 16; ++t) {
    const int cur = t & 1;
    if (t + 1 < 16) {
      stage(cur ^ 1, (t + 1) * 64);
      asm volatile("s_waitcnt vmcnt(6)" ::: "memory");  // this tile done; next 6 in flight
    } else {
      asm volatile("s_waitcnt vmcnt(0)" ::: "memory");
    }
    __builtin_amdgcn_s_barrier();
    __builtin_amdgcn_sched_barrier(0);
    const char* AB = (const char*)&As[cur * 8192];
    const char* BB = (const char*)&Bs[cur * 4096];
#pragma unroll
    for (int ks = 0; ks < 2; ++ks) {
      bf16x8 af[4], bfr[2];
#pragma unroll
      for (int mf = 0; mf < 4; ++mf) {
        int row = wm * 64 + mf * 16 + cc;
        af[mf] = *(const bf16x8*)(AB + row * 128 + ((ks * 64 + g * 16) ^ ((row & 7) << 4)));
      }
#pragma unroll
      for (int nf = 0; nf < 2; ++nf) {
        int row = wn * 32 + nf * 16 + cc;
        bfr[nf] = *(const bf16x8*)(BB + row * 128 + ((ks * 64 + g * 16) ^ ((row & 7) << 4)));
      }
#pragma unroll
      for (int mf = 0; mf < 4; ++mf)
#pragma unroll
        for (int nf = 0; nf < 2; ++nf)
          acc[mf][nf] = mfma16(af[mf], bfr[nf], acc[mf][nf]);
    }
    __builtin_amdgcn_s_barrier();   // WAR guard; no vmcnt drain
  }

  // ---- epilogue: single 16KB pane (reuse As region), XOR-swizzled writes ----
  __syncthreads();
  {
    char* P = (char*)SMEM;
    const float* bptr = bias + head * 192 + type * 64;
#pragma unroll
    for (int mf = 0; mf < 4; ++mf) {
#pragma unroll
      for (int nf = 0; nf < 2; ++nf) {
        int d = wn * 32 + nf * 16 + cc;
        float bv = bptr[d];
#pragma unroll
        for (int r = 0; r < 4; ++r) {
          int ml = wm * 64 + mf * 16 + g * 4 + r;
          float val = acc[mf][nf][r] + bv;
          if (type == 0) val *= QSCALE;
          u16 hv = cvt_bf(val);
          if (type == 2) *(u16*)(P + d * 256 + ((ml * 2) ^ ((d & 7) << 5))) = hv;
          else           *(u16*)(P + ml * 128 + ((d * 2) ^ (((ml >> 2) & 3) << 5))) = hv;
        }
      }
    }
  }
  __syncthreads();
  const int ls0 = m0 & (LSEQ - 1);
  const int bh = bb * NH + head;
  char* P = (char*)SMEM;
  if (type == 2) {
    // V: 64 rows(d) x 256B of ml; dst row stride LSEQ elems
    u16* dstb = Vo + (size_t)bh * HDIM * LSEQ + ls0;
#pragma unroll
    for (int it = 0; it < 4; ++it) {
      int idx = it * 256 + tid;
      int row = idx >> 4;
      int colB = (idx & 15) * 16;
      int4 v = *(const int4*)(P + row * 256 + (colB ^ ((row & 7) << 5)));
      *(int4*)((char*)(dstb + (size_t)row * LSEQ) + colB) = v;
    }
  } else {
    // Q/K: 128 rows(ml) x 128B -> contiguous 16KB at dst
    u16* dst = (type == 0 ? Qo : Ko) + ((size_t)bh * LSEQ + ls0) * HDIM;
#pragma unroll
    for (int it = 0; it < 4; ++it) {
      int idx = it * 256 + tid;
      int row = idx >> 3;
      int colB = (idx & 7) * 16;
      int4 v = *(const int4*)(P + row * 128 + (colB ^ (((row >> 2) & 3) << 5)));
      *(int4*)((char*)dst + row * 128 + colB) = v;
    }
  }
}

// ---------------- out-proj GEMM (R17, unchanged) ----------------
__launch_bounds__(256, 2)
__global__ void gemm_out(const u16* __restrict__ A, const u16* __restrict__ Bt,
                         const float* __restrict__ bias, float* __restrict__ Out) {
  __shared__ __attribute__((aligned(16))) u16 SMEM[2 * 4096 + 2 * 8192];
  u16* As = SMEM;                    // [2][64*64]
  u16* Bs = SMEM + 2 * 4096;         // [2][128*64]
  const int tid = threadIdx.x;
  const int w = tid >> 6, l = tid & 63;
  const int g = l >> 4, cc = l & 15;
  const int orig = blockIdx.y * 8 + blockIdx.x;
  const int wgid = (orig & 7) * 64 + (orig >> 3);   // XCD-bijective (512 % 8 == 0)
  const int m0 = (wgid >> 3) * 64;
  const int n0 = (wgid & 7) * 128;
  const int wm = w >> 1, wn = w & 1;
  const int K = 1024;
  const int srow8 = tid >> 3;       // 0..31 row within call
  const int chunk = tid & 7;

  auto stage = [&](int buf, int k0) {
#pragma unroll
    for (int c = 0; c < 2; ++c) {
      int R = c * 32 + srow8;                 // 0..63 A-panel row
      int col = (chunk ^ (R & 7)) * 8;        // pre-swizzled source (elems)
      async16((char*)As + buf * 8192 + c * 4096 + w * 1024,
              A + (size_t)(m0 + R) * K + k0 + col);
    }
#pragma unroll
    for (int c = 0; c < 4; ++c) {
      int R = c * 32 + srow8;                 // 0..127 B-panel row
      int col = (chunk ^ (R & 7)) * 8;
      async16((char*)Bs + buf * 16384 + c * 4096 + w * 1024,
              Bt + (size_t)(n0 + R) * K + k0 + col);
    }
  };

  f32x4 acc[2][4] = {};
  stage(0, 0);
  for (int t = 0; t < 16; ++t) {
    const int cur = t & 1;
    if (t + 1 < 16) {
      stage(cur ^ 1, (t + 1) * 64);
      asm volatile("s_waitcnt vmcnt(6)" ::: "memory");  // this tile done; next 6 in flight
    } else {
      asm volatile("s_waitcnt vmcnt(0)" ::: "memory");
    }
    __builtin_amdgcn_s_barrier();
    __builtin_amdgcn_sched_barrier(0);
    const char* AB = (const char*)As + cur * 8192;
    const char* BB = (const char*)Bs + cur * 16384;
#pragma unroll
    for (int ks = 0; ks < 2; ++ks) {
      bf16x8 af[2], bfr[4];
#pragma unroll
      for (int mf = 0; mf < 2; ++mf) {
        int row = wm * 32 + mf * 16 + cc;
        af[mf] = *(const bf16x8*)(AB + row * 128 + ((ks * 64 + g * 16) ^ ((row & 7) << 4)));
      }
#pragma unroll
      for (int nf = 0; nf < 4; ++nf) {
        int row = wn * 64 + nf * 16 + cc;
        bfr[nf] = *(const bf16x8*)(BB + row * 128 + ((ks * 64 + g * 16) ^ ((row & 7) << 4)));
      }
#pragma unroll
      for (int mf = 0; mf < 2; ++mf)
#pragma unroll
        for (int nf = 0; nf < 4; ++nf)
          acc[mf][nf] = mfma16(af[mf], bfr[nf], acc[mf][nf]);
    }
    __builtin_amdgcn_s_barrier();   // WAR guard; no vmcnt drain
  }

  // epilogue: direct fp32 stores + bias
#pragma unroll
  for (int mf = 0; mf < 2; ++mf) {
#pragma unroll
    for (int nf = 0; nf < 4; ++nf) {
      int n = n0 + wn * 64 + nf * 16 + cc;
      float bv = bias[n];
#pragma unroll
      for (int r = 0; r < 4; ++r) {
        int m = m0 + wm * 32 + mf * 16 + g * 4 + r;
        Out[(size_t)m * EMB + n] = acc[mf][nf][r] + bv;
      }
    }
  }
}

// ---------------- flash attention + fused meanv (R14, unchanged: meanv fills Y) ----------------
__launch_bounds__(256)
__global__ void attn_fwd(const u16* __restrict__ Q, const u16* __restrict__ Kb,
                         const u16* __restrict__ Vt, const int* __restrict__ mask_len,
                         u16* __restrict__ Y) {
  __shared__ __attribute__((aligned(16))) u16 Ks[2][64 * 64];
  __shared__ __attribute__((aligned(16))) u16 Vs[2][64 * 64];
  __shared__ __attribute__((aligned(16))) u16 Ps[4 * 16 * 64];
  const int tid = threadIdx.x;
  const int i = blockIdx.x;

  if (i >= 1024) {
    float* partial = (float*)Ks;
    u16* mv = (u16*)((char*)Ks + 1024);
    int bh = i - 1024, b = bh >> 4, h = bh & (NH - 1);
    int d = tid >> 2, part = tid & 3;
    const u16* src = Vt + ((size_t)bh * HDIM + d) * LSEQ + part * 512;
    float s = 0.f;
    for (int ii = 0; ii < 512; ii += 8) {
      u16x8 v = *(const u16x8*)&src[ii];
#pragma unroll
      for (int jj = 0; jj < 8; ++jj) s += bf2f(v[jj]);
    }
    partial[tid] = s;
    __syncthreads();
    if (part == 0) {
      float t = partial[tid] + partial[tid + 1] + partial[tid + 2] + partial[tid + 3];
      mv[d] = cvt_bf(t * (1.0f / (float)LSEQ));
    }
    __syncthreads();
    int lo = mask_len[b];
    if (lo < 0) lo = 0;
    if (lo > LSEQ) lo = LSEQ;
    int total = (LSEQ - lo) * HDIM;
    for (int idx = tid; idx < total; idx += 256) {
      int row = lo + (idx >> 6), dd = idx & 63;
      Y[((size_t)b * LSEQ + row) * EMB + h * HDIM + dd] = mv[dd];
    }
    return;
  }

  const int w = tid >> 6, l = tid & 63;
  const int g = l >> 4, cc = l & 15;
  const int bh = i & 31;
  const int k = i >> 5, grp = k >> 3, j = k & 7;
  int qblk;
  if (grp == 0) qblk = 31 - j;
  else if (grp == 1) qblk = j;
  else if (grp == 2) qblk = 23 - j;
  else qblk = 8 + j;
  const int q0 = qblk * 64;
  const int nt = qblk + 1;
  const int b = bh >> 4, h = bh & (NH - 1);

  const int lo = mask_len[b];
  if (q0 >= lo) return;

  const int sr = w * 8 + (l >> 3);
  const int pb = (l & 7) * 16;
  char* Pw = (char*)&Ps[w * 16 * 64];
  const int xc = (cc & 7) << 4;

  auto stageKV = [&](int buf, int t) {
    const int kv0 = t * 64;
#pragma unroll
    for (int ch = 0; ch < 2; ++ch) {
      int R = sr + ch * 32;
      int dcol = (pb ^ ((R & 7) << 4)) >> 1;
      async16((char*)Ks[buf] + ch * 4096 + w * 1024,
              Kb + ((size_t)bh * LSEQ + kv0 + R) * HDIM + dcol);
      async16((char*)Vs[buf] + ch * 4096 + w * 1024,
              Vt + ((size_t)bh * HDIM + R) * LSEQ + kv0 + dcol);
    }
  };

  const u16* Qg = Q + ((size_t)bh * LSEQ + q0 + w * 16) * HDIM;
  bf16x8 qf0 = *(const bf16x8*)&Qg[cc * HDIM + g * 8];
  bf16x8 qf1 = *(const bf16x8*)&Qg[cc * HDIM + 32 + g * 8];

  bf16x8 onesf;
#pragma unroll
  for (int z = 0; z < 8; ++z) onesf[z] = (__bf16)1.0f;

  f32x4 o[4] = {};
  f32x4 ls = {};

  stageKV(0, 0);

  for (int t = 0; t < nt; ++t) {
    const int cur = t & 1;
    if (t + 1 < nt) {
      stageKV(cur ^ 1, t + 1);
      asm volatile("s_waitcnt vmcnt(4)" ::: "memory");
    } else {
      asm volatile("s_waitcnt vmcnt(0)" ::: "memory");
    }
    __builtin_amdgcn_s_barrier();
    __builtin_amdgcn_sched_barrier(0);
    const char* KsB = (const char*)Ks[cur];
    const char* VsB = (const char*)Vs[cur];

    f32x4 sf[4] = {};
    __builtin_amdgcn_s_setprio(1);
#pragma unroll
    for (int nf = 0; nf < 4; ++nf) {
      bf16x8 kf0 = *(const bf16x8*)(KsB + (nf * 16 + cc) * 128 + ((g * 16) ^ xc));
      bf16x8 kf1 = *(const bf16x8*)(KsB + (nf * 16 + cc) * 128 + ((64 + g * 16) ^ xc));
      sf[nf] = mfma16(qf0, kf0, sf[nf]);
      sf[nf] = mfma16(qf1, kf1, sf[nf]);
    }
    __builtin_amdgcn_s_setprio(0);

    if (t == nt - 1) {
#pragma unroll
      for (int nf = 0; nf < 4; ++nf) {
        int kvl = nf * 16 + cc;
#pragma unroll
        for (int r = 0; r < 4; ++r)
          if (kvl > w * 16 + g * 4 + r) sf[nf][r] = -1e30f;
      }
    }

#pragma unroll
    for (int r = 0; r < 4; ++r) {
      int q = g * 4 + r;
      int xr = (q & 7) << 4;
#pragma unroll
      for (int nf = 0; nf < 4; ++nf) {
        float pv = EXP2(sf[nf][r]);
        *(u16*)(Pw + q * 128 + (((nf * 16 + cc) * 2) ^ xr)) = cvt_bf(pv);
      }
    }
    asm volatile("s_waitcnt lgkmcnt(0)" ::: "memory");
    __builtin_amdgcn_sched_barrier(0);

    bf16x8 pf0 = *(const bf16x8*)(Pw + cc * 128 + ((g * 16) ^ xc));
    bf16x8 pf1 = *(const bf16x8*)(Pw + cc * 128 + ((64 + g * 16) ^ xc));
    __builtin_amdgcn_s_setprio(1);
    ls = mfma16(pf1, onesf, mfma16(pf0, onesf, ls));
#pragma unroll
    for (int nf = 0; nf < 4; ++nf) {
      bf16x8 vf0 = *(const bf16x8*)(VsB + (nf * 16 + cc) * 128 + ((g * 16) ^ xc));
      bf16x8 vf1 = *(const bf16x8*)(VsB + (nf * 16 + cc) * 128 + ((64 + g * 16) ^ xc));
      o[nf] = mfma16(pf0, vf0, o[nf]);
      o[nf] = mfma16(pf1, vf1, o[nf]);
    }
    __builtin_amdgcn_s_setprio(0);
    __builtin_amdgcn_s_barrier();
  }

#pragma unroll
  for (int r = 0; r < 4; ++r) {
    int row = q0 + w * 16 + g * 4 + r;
    if (row < lo) {
      float inv = 1.0f / ls[r];
      size_t base = ((size_t)b * LSEQ + row) * EMB + h * HDIM;
#pragma unroll
      for (int nf = 0; nf < 4; ++nf)
        Y[base + nf * 16 + cc] = cvt_bf(o[nf][r] * inv);
    }
  }
}

// ---------------- launch ----------------
extern "C" void kernel_launch(void* const* d_in, const int* in_sizes, int n_in,
                              void* d_out, int out_size, void* d_ws, size_t ws_size,
                              hipStream_t stream) {
  (void)in_sizes; (void)n_in; (void)out_size; (void)ws_size;
  const float* x    = (const float*)d_in[0];
  const float* Wqkv = (const float*)d_in[1];
  const float* bqkv = (const float*)d_in[2];
  const float* Wo   = (const float*)d_in[3];
  const float* bo   = (const float*)d_in[4];
  const int* mask_len = (const int*)d_in[5];
  float* out = (float*)d_out;

  u16* ws = (u16*)d_ws;
  u16* xb    = ws;                              // 4M elems (x bf16) — reused as Y later
  u16* wqkvt = ws + (size_t)4 * 1024 * 1024;    // 3M (W_qkv^T bf16)
  u16* wot   = wqkvt + (size_t)3 * 1024 * 1024; // 1M (W_o^T bf16)
  u16* Qb    = wot + (size_t)1024 * 1024;       // 4M
  u16* Kb    = Qb + (size_t)4 * 1024 * 1024;    // 4M
  u16* Vtb   = Kb + (size_t)4 * 1024 * 1024;    // 4M
  u16* Yb    = xb;                              // alias: x dead after gemm_qkv

  prep<<<6144, 256, 0, stream>>>(x, xb, Wqkv, wqkvt, Wo, wot);
  gemm_qkv<<<dim3(48, 32), 256, 0, stream>>>(xb, wqkvt, bqkv, Qb, Kb, Vtb, mask_len);
  attn_fwd<<<1056, 256, 0, stream>>>(Qb, Kb, Vtb, mask_len, Yb);
  gemm_out<<<dim3(8, 64), 256, 0, stream>>>(Yb, wot, bo, out);
}

// Round 19
// 91.905 us; speedup vs baseline: 1.0222x; 1.0222x over previous
//
#include <hip/hip_runtime.h>

typedef unsigned short u16;
typedef unsigned int u32;
typedef __bf16 bf16x8 __attribute__((ext_vector_type(8)));
typedef float f32x4 __attribute__((ext_vector_type(4)));
typedef u16 u16x2 __attribute__((ext_vector_type(2)));
typedef u16 u16x4 __attribute__((ext_vector_type(4)));
typedef u16 u16x8 __attribute__((ext_vector_type(8)));

#define LSEQ 2048
#define EMB  1024
#define NH   16
#define HDIM 64

// Q pre-scale: 1/sqrt(64) * log2(e)  (softmax computed in base 2)
#define QSCALE 0.1803368808f

#if __has_builtin(__builtin_amdgcn_exp2f)
#define EXP2(x) __builtin_amdgcn_exp2f(x)
#else
#define EXP2(x) __expf((x) * 0.6931471805599453f)
#endif

__device__ __forceinline__ u16 cvt_bf(float f) {
  __bf16 h = (__bf16)f;
  return __builtin_bit_cast(u16, h);
}
__device__ __forceinline__ float bf2f(u16 v) {
  return __uint_as_float(((unsigned)v) << 16);
}
__device__ __forceinline__ void async16(void* lds, const void* g) {
  __builtin_amdgcn_global_load_lds((const __attribute__((address_space(1))) void*)g,
                                   (__attribute__((address_space(3))) void*)lds, 16, 0, 0);
}
__device__ __forceinline__ f32x4 mfma16(bf16x8 a, bf16x8 b, f32x4 c) {
  return __builtin_amdgcn_mfma_f32_16x16x32_bf16(a, b, c, 0, 0, 0);
}

// ---------------- fused prep: x conversion + both weight transposes ----------------
// R19: transpose k-tile widened to 64; each lane stores u16x2 -> 128B/wave-instr
// full-line stores (was 64B half-line). Transpose blocks 2048 (bx 0..127, by 0..15).
__global__ void prep(const float* __restrict__ x, u16* __restrict__ xb,
                     const float* __restrict__ Wqkv, u16* __restrict__ WqkvT,
                     const float* __restrict__ Wo, u16* __restrict__ WoT) {
  __shared__ float tile[64][33];
  const int bid = blockIdx.x;
  const int tid = threadIdx.x;
  if (bid < 2048) {
    const int n4 = 1024 * 1024;
    for (int i = bid * 256 + tid; i < n4; i += 2048 * 256) {
      float4 v = ((const float4*)x)[i];
      u16x4 o = { cvt_bf(v.x), cvt_bf(v.y), cvt_bf(v.z), cvt_bf(v.w) };
      ((u16x4*)xb)[i] = o;
    }
    return;
  }
  const int idx = bid - 2048;          // 0..2047
  const int bx = idx & 127, by = idx >> 7;   // by 0..15
  const int Kd = 1024;
  const float* in;
  u16* out;
  int Nd, n0;
  if (bx < 96) { in = Wqkv; out = WqkvT; Nd = 3072; n0 = bx * 32; }
  else         { in = Wo;   out = WoT;   Nd = 1024; n0 = (bx - 96) * 32; }
  const int k0 = by * 64;
  const int tx = tid & 31, ty = tid >> 5;   // (32,8)
#pragma unroll
  for (int i = 0; i < 8; ++i)
    tile[ty + i * 8][tx] = in[(size_t)(k0 + ty + i * 8) * Nd + n0 + tx];
  __syncthreads();
#pragma unroll
  for (int i = 0; i < 4; ++i) {
    int nl = ty + i * 8;
    u16x2 v = { cvt_bf(tile[2 * tx][nl]), cvt_bf(tile[2 * tx + 1][nl]) };
    *(u16x2*)&out[(size_t)(n0 + nl) * Kd + k0 + 2 * tx] = v;
  }
}

// ---------------- QKV GEMM (R14 proven version: BN=128 head-pair typed blocks) ----------------
__launch_bounds__(256, 2)
__global__ void gemm_qkv(const u16* __restrict__ A, const u16* __restrict__ Bt,
                         const float* __restrict__ bias,
                         u16* __restrict__ Qo, u16* __restrict__ Ko, u16* __restrict__ Vo,
                         const int* __restrict__ mask_len) {
  __shared__ __attribute__((aligned(16))) u16 SMEM[4 * 8192];  // As[2][128*64] Bs[2][128*64]
  u16* As = SMEM;
  u16* Bs = SMEM + 2 * 8192;
  const int tid = threadIdx.x;
  const int w = tid >> 6, l = tid & 63;
  const int g = l >> 4, cc = l & 15;
  const int orig = blockIdx.y * 24 + blockIdx.x;
  const int wgid = (orig & 7) * 96 + (orig >> 3);   // XCD-bijective (768 % 8 == 0)
  const int m0 = (wgid / 24) * 128;
  const int tb = wgid % 24;
  const int type = tb >> 3, tbh = tb & 7;           // 0=Q 1=K 2=V; head pair 2*tbh+{0,1}
  const int bb = m0 >> 11;
  const int lo = mask_len[bb];
  if (type < 2 && (m0 & (LSEQ - 1)) >= lo) return;  // dead Q/K rows
  const int wm = w >> 1, wn = w & 1;
  const int K = 1024;

  const int srow8 = tid >> 3;       // 0..31 row within call
  const int chunk = tid & 7;
  auto stage = [&](int buf, int k0) {
#pragma unroll
    for (int c = 0; c < 4; ++c) {
      int R = c * 32 + srow8;                 // 0..127 panel row
      int col = (chunk ^ (R & 7)) * 8;        // pre-swizzled source (elems)
      async16((char*)&As[buf * 8192] + c * 4096 + w * 1024,
              A + (size_t)(m0 + R) * K + k0 + col);
      int gR = (2 * tbh + (R >> 6)) * 192 + type * 64 + (R & 63);
      async16((char*)&Bs[buf * 8192] + c * 4096 + w * 1024,
              Bt + (size_t)gR * K + k0 + col);
    }
  };

  f32x4 acc[4][4] = {};
  stage(0, 0);
  for (int t = 0; t < 16; ++t) {
    const int cur = t & 1;
    if (t + 1 < 16) {
      stage(cur ^ 1, (t + 1) * 64);
      asm volatile("s_waitcnt vmcnt(8)" ::: "memory");
    } else {
      asm volatile("s_waitcnt vmcnt(0)" ::: "memory");
    }
    __builtin_amdgcn_s_barrier();
    __builtin_amdgcn_sched_barrier(0);
    const char* AB = (const char*)&As[cur * 8192];
    const char* BB = (const char*)&Bs[cur * 8192];
#pragma unroll
    for (int ks = 0; ks < 2; ++ks) {
      bf16x8 af[4], bfr[4];
#pragma unroll
      for (int mf = 0; mf < 4; ++mf) {
        int row = wm * 64 + mf * 16 + cc;
        af[mf] = *(const bf16x8*)(AB + row * 128 + ((ks * 64 + g * 16) ^ ((row & 7) << 4)));
      }
#pragma unroll
      for (int nf = 0; nf < 4; ++nf) {
        int row = wn * 64 + nf * 16 + cc;
        bfr[nf] = *(const bf16x8*)(BB + row * 128 + ((ks * 64 + g * 16) ^ ((row & 7) << 4)));
      }
#pragma unroll
      for (int mf = 0; mf < 4; ++mf)
#pragma unroll
        for (int nf = 0; nf < 4; ++nf)
          acc[mf][nf] = mfma16(af[mf], bfr[nf], acc[mf][nf]);
    }
    __builtin_amdgcn_s_barrier();
  }

  __syncthreads();
  {
    char* P = (char*)SMEM + wn * 16384;
    const float* bptr = bias + (2 * tbh + wn) * 192 + type * 64;
#pragma unroll
    for (int mf = 0; mf < 4; ++mf) {
#pragma unroll
      for (int nf = 0; nf < 4; ++nf) {
        int d = nf * 16 + cc;
        float bv = bptr[d];
#pragma unroll
        for (int r = 0; r < 4; ++r) {
          int ml = wm * 64 + mf * 16 + g * 4 + r;
          float val = acc[mf][nf][r] + bv;
          if (type == 0) val *= QSCALE;
          u16 hv = cvt_bf(val);
          if (type == 2) *(u16*)(P + d * 256 + ((ml * 2) ^ ((d & 7) << 5))) = hv;
          else           *(u16*)(P + ml * 128 + ((d * 2) ^ (((ml >> 2) & 3) << 5))) = hv;
        }
      }
    }
  }
  __syncthreads();
  const int ls0 = m0 & (LSEQ - 1);
#pragma unroll
  for (int wi = 0; wi < 2; ++wi) {
    const int bh = bb * NH + 2 * tbh + wi;
    char* P = (char*)SMEM + wi * 16384;
    if (type == 2) {
      u16* dstb = Vo + (size_t)bh * HDIM * LSEQ + ls0;
#pragma unroll
      for (int it = 0; it < 4; ++it) {
        int idx = it * 256 + tid;
        int row = idx >> 4;
        int colB = (idx & 15) * 16;
        int4 v = *(const int4*)(P + row * 256 + (colB ^ ((row & 7) << 5)));
        *(int4*)((char*)(dstb + (size_t)row * LSEQ) + colB) = v;
      }
    } else {
      u16* dst = (type == 0 ? Qo : Ko) + ((size_t)bh * LSEQ + ls0) * HDIM;
#pragma unroll
      for (int it = 0; it < 4; ++it) {
        int idx = it * 256 + tid;
        int row = idx >> 3;
        int colB = (idx & 7) * 16;
        int4 v = *(const int4*)(P + row * 128 + (colB ^ (((row >> 2) & 3) << 5)));
        *(int4*)((char*)dst + row * 128 + colB) = v;
      }
    }
  }
}

// ---------------- out-proj GEMM (R17, unchanged) ----------------
__launch_bounds__(256, 2)
__global__ void gemm_out(const u16* __restrict__ A, const u16* __restrict__ Bt,
                         const float* __restrict__ bias, float* __restrict__ Out) {
  __shared__ __attribute__((aligned(16))) u16 SMEM[2 * 4096 + 2 * 8192];
  u16* As = SMEM;                    // [2][64*64]
  u16* Bs = SMEM + 2 * 4096;         // [2][128*64]
  const int tid = threadIdx.x;
  const int w = tid >> 6, l = tid & 63;
  const int g = l >> 4, cc = l & 15;
  const int orig = blockIdx.y * 8 + blockIdx.x;
  const int wgid = (orig & 7) * 64 + (orig >> 3);   // XCD-bijective (512 % 8 == 0)
  const int m0 = (wgid >> 3) * 64;
  const int n0 = (wgid & 7) * 128;
  const int wm = w >> 1, wn = w & 1;
  const int K = 1024;
  const int srow8 = tid >> 3;       // 0..31 row within call
  const int chunk = tid & 7;

  auto stage = [&](int buf, int k0) {
#pragma unroll
    for (int c = 0; c < 2; ++c) {
      int R = c * 32 + srow8;                 // 0..63 A-panel row
      int col = (chunk ^ (R & 7)) * 8;        // pre-swizzled source (elems)
      async16((char*)As + buf * 8192 + c * 4096 + w * 1024,
              A + (size_t)(m0 + R) * K + k0 + col);
    }
#pragma unroll
    for (int c = 0; c < 4; ++c) {
      int R = c * 32 + srow8;                 // 0..127 B-panel row
      int col = (chunk ^ (R & 7)) * 8;
      async16((char*)Bs + buf * 16384 + c * 4096 + w * 1024,
              Bt + (size_t)(n0 + R) * K + k0 + col);
    }
  };

  f32x4 acc[2][4] = {};
  stage(0, 0);
  for (int t = 0; t < 16; ++t) {
    const int cur = t & 1;
    if (t + 1 < 16) {
      stage(cur ^ 1, (t + 1) * 64);
      asm volatile("s_waitcnt vmcnt(6)" ::: "memory");  // this tile done; next 6 in flight
    } else {
      asm volatile("s_waitcnt vmcnt(0)" ::: "memory");
    }
    __builtin_amdgcn_s_barrier();
    __builtin_amdgcn_sched_barrier(0);
    const char* AB = (const char*)As + cur * 8192;
    const char* BB = (const char*)Bs + cur * 16384;
#pragma unroll
    for (int ks = 0; ks < 2; ++ks) {
      bf16x8 af[2], bfr[4];
#pragma unroll
      for (int mf = 0; mf < 2; ++mf) {
        int row = wm * 32 + mf * 16 + cc;
        af[mf] = *(const bf16x8*)(AB + row * 128 + ((ks * 64 + g * 16) ^ ((row & 7) << 4)));
      }
#pragma unroll
      for (int nf = 0; nf < 4; ++nf) {
        int row = wn * 64 + nf * 16 + cc;
        bfr[nf] = *(const bf16x8*)(BB + row * 128 + ((ks * 64 + g * 16) ^ ((row & 7) << 4)));
      }
#pragma unroll
      for (int mf = 0; mf < 2; ++mf)
#pragma unroll
        for (int nf = 0; nf < 4; ++nf)
          acc[mf][nf] = mfma16(af[mf], bfr[nf], acc[mf][nf]);
    }
    __builtin_amdgcn_s_barrier();   // WAR guard; no vmcnt drain
  }

  // epilogue: direct fp32 stores + bias
#pragma unroll
  for (int mf = 0; mf < 2; ++mf) {
#pragma unroll
    for (int nf = 0; nf < 4; ++nf) {
      int n = n0 + wn * 64 + nf * 16 + cc;
      float bv = bias[n];
#pragma unroll
      for (int r = 0; r < 4; ++r) {
        int m = m0 + wm * 32 + mf * 16 + g * 4 + r;
        Out[(size_t)m * EMB + n] = acc[mf][nf][r] + bv;
      }
    }
  }
}

// ---------------- flash attention + fused meanv (R14/R17, unchanged) ----------------
__launch_bounds__(256)
__global__ void attn_fwd(const u16* __restrict__ Q, const u16* __restrict__ Kb,
                         const u16* __restrict__ Vt, const int* __restrict__ mask_len,
                         u16* __restrict__ Y) {
  __shared__ __attribute__((aligned(16))) u16 Ks[2][64 * 64];
  __shared__ __attribute__((aligned(16))) u16 Vs[2][64 * 64];
  __shared__ __attribute__((aligned(16))) u16 Ps[4 * 16 * 64];
  const int tid = threadIdx.x;
  const int i = blockIdx.x;

  if (i >= 1024) {
    float* partial = (float*)Ks;
    u16* mv = (u16*)((char*)Ks + 1024);
    int bh = i - 1024, b = bh >> 4, h = bh & (NH - 1);
    int d = tid >> 2, part = tid & 3;
    const u16* src = Vt + ((size_t)bh * HDIM + d) * LSEQ + part * 512;
    float s = 0.f;
    for (int ii = 0; ii < 512; ii += 8) {
      u16x8 v = *(const u16x8*)&src[ii];
#pragma unroll
      for (int jj = 0; jj < 8; ++jj) s += bf2f(v[jj]);
    }
    partial[tid] = s;
    __syncthreads();
    if (part == 0) {
      float t = partial[tid] + partial[tid + 1] + partial[tid + 2] + partial[tid + 3];
      mv[d] = cvt_bf(t * (1.0f / (float)LSEQ));
    }
    __syncthreads();
    int lo = mask_len[b];
    if (lo < 0) lo = 0;
    if (lo > LSEQ) lo = LSEQ;
    int total = (LSEQ - lo) * HDIM;
    for (int idx = tid; idx < total; idx += 256) {
      int row = lo + (idx >> 6), dd = idx & 63;
      Y[((size_t)b * LSEQ + row) * EMB + h * HDIM + dd] = mv[dd];
    }
    return;
  }

  const int w = tid >> 6, l = tid & 63;
  const int g = l >> 4, cc = l & 15;
  const int bh = i & 31;
  const int k = i >> 5, grp = k >> 3, j = k & 7;
  int qblk;
  if (grp == 0) qblk = 31 - j;
  else if (grp == 1) qblk = j;
  else if (grp == 2) qblk = 23 - j;
  else qblk = 8 + j;
  const int q0 = qblk * 64;
  const int nt = qblk + 1;
  const int b = bh >> 4, h = bh & (NH - 1);

  const int lo = mask_len[b];
  if (q0 >= lo) return;

  const int sr = w * 8 + (l >> 3);
  const int pb = (l & 7) * 16;
  char* Pw = (char*)&Ps[w * 16 * 64];
  const int xc = (cc & 7) << 4;

  auto stageKV = [&](int buf, int t) {
    const int kv0 = t * 64;
#pragma unroll
    for (int ch = 0; ch < 2; ++ch) {
      int R = sr + ch * 32;
      int dcol = (pb ^ ((R & 7) << 4)) >> 1;
      async16((char*)Ks[buf] + ch * 4096 + w * 1024,
              Kb + ((size_t)bh * LSEQ + kv0 + R) * HDIM + dcol);
      async16((char*)Vs[buf] + ch * 4096 + w * 1024,
              Vt + ((size_t)bh * HDIM + R) * LSEQ + kv0 + dcol);
    }
  };

  const u16* Qg = Q + ((size_t)bh * LSEQ + q0 + w * 16) * HDIM;
  bf16x8 qf0 = *(const bf16x8*)&Qg[cc * HDIM + g * 8];
  bf16x8 qf1 = *(const bf16x8*)&Qg[cc * HDIM + 32 + g * 8];

  bf16x8 onesf;
#pragma unroll
  for (int z = 0; z < 8; ++z) onesf[z] = (__bf16)1.0f;

  f32x4 o[4] = {};
  f32x4 ls = {};

  stageKV(0, 0);

  for (int t = 0; t < nt; ++t) {
    const int cur = t & 1;
    if (t + 1 < nt) {
      stageKV(cur ^ 1, t + 1);
      asm volatile("s_waitcnt vmcnt(4)" ::: "memory");
    } else {
      asm volatile("s_waitcnt vmcnt(0)" ::: "memory");
    }
    __builtin_amdgcn_s_barrier();
    __builtin_amdgcn_sched_barrier(0);
    const char* KsB = (const char*)Ks[cur];
    const char* VsB = (const char*)Vs[cur];

    f32x4 sf[4] = {};
    __builtin_amdgcn_s_setprio(1);
#pragma unroll
    for (int nf = 0; nf < 4; ++nf) {
      bf16x8 kf0 = *(const bf16x8*)(KsB + (nf * 16 + cc) * 128 + ((g * 16) ^ xc));
      bf16x8 kf1 = *(const bf16x8*)(KsB + (nf * 16 + cc) * 128 + ((64 + g * 16) ^ xc));
      sf[nf] = mfma16(qf0, kf0, sf[nf]);
      sf[nf] = mfma16(qf1, kf1, sf[nf]);
    }
    __builtin_amdgcn_s_setprio(0);

    if (t == nt - 1) {
#pragma unroll
      for (int nf = 0; nf < 4; ++nf) {
        int kvl = nf * 16 + cc;
#pragma unroll
        for (int r = 0; r < 4; ++r)
          if (kvl > w * 16 + g * 4 + r) sf[nf][r] = -1e30f;
      }
    }

#pragma unroll
    for (int r = 0; r < 4; ++r) {
      int q = g * 4 + r;
      int xr = (q & 7) << 4;
#pragma unroll
      for (int nf = 0; nf < 4; ++nf) {
        float pv = EXP2(sf[nf][r]);
        *(u16*)(Pw + q * 128 + (((nf * 16 + cc) * 2) ^ xr)) = cvt_bf(pv);
      }
    }
    asm volatile("s_waitcnt lgkmcnt(0)" ::: "memory");
    __builtin_amdgcn_sched_barrier(0);

    bf16x8 pf0 = *(const bf16x8*)(Pw + cc * 128 + ((g * 16) ^ xc));
    bf16x8 pf1 = *(const bf16x8*)(Pw + cc * 128 + ((64 + g * 16) ^ xc));
    __builtin_amdgcn_s_setprio(1);
    ls = mfma16(pf1, onesf, mfma16(pf0, onesf, ls));
#pragma unroll
    for (int nf = 0; nf < 4; ++nf) {
      bf16x8 vf0 = *(const bf16x8*)(VsB + (nf * 16 + cc) * 128 + ((g * 16) ^ xc));
      bf16x8 vf1 = *(const bf16x8*)(VsB + (nf * 16 + cc) * 128 + ((64 + g * 16) ^ xc));
      o[nf] = mfma16(pf0, vf0, o[nf]);
      o[nf] = mfma16(pf1, vf1, o[nf]);
    }
    __builtin_amdgcn_s_setprio(0);
    __builtin_amdgcn_s_barrier();
  }

#pragma unroll
  for (int r = 0; r < 4; ++r) {
    int row = q0 + w * 16 + g * 4 + r;
    if (row < lo) {
      float inv = 1.0f / ls[r];
      size_t base = ((size_t)b * LSEQ + row) * EMB + h * HDIM;
#pragma unroll
      for (int nf = 0; nf < 4; ++nf)
        Y[base + nf * 16 + cc] = cvt_bf(o[nf][r] * inv);
    }
  }
}

// ---------------- launch ----------------
extern "C" void kernel_launch(void* const* d_in, const int* in_sizes, int n_in,
                              void* d_out, int out_size, void* d_ws, size_t ws_size,
                              hipStream_t stream) {
  (void)in_sizes; (void)n_in; (void)out_size; (void)ws_size;
  const float* x    = (const float*)d_in[0];
  const float* Wqkv = (const float*)d_in[1];
  const float* bqkv = (const float*)d_in[2];
  const float* Wo   = (const float*)d_in[3];
  const float* bo   = (const float*)d_in[4];
  const int* mask_len = (const int*)d_in[5];
  float* out = (float*)d_out;

  u16* ws = (u16*)d_ws;
  u16* xb    = ws;                              // 4M elems (x bf16) — reused as Y later
  u16* wqkvt = ws + (size_t)4 * 1024 * 1024;    // 3M (W_qkv^T bf16)
  u16* wot   = wqkvt + (size_t)3 * 1024 * 1024; // 1M (W_o^T bf16)
  u16* Qb    = wot + (size_t)1024 * 1024;       // 4M
  u16* Kb    = Qb + (size_t)4 * 1024 * 1024;    // 4M
  u16* Vtb   = Kb + (size_t)4 * 1024 * 1024;    // 4M
  u16* Yb    = xb;                              // alias: x dead after gemm_qkv

  prep<<<4096, 256, 0, stream>>>(x, xb, Wqkv, wqkvt, Wo, wot);
  gemm_qkv<<<dim3(24, 32), 256, 0, stream>>>(xb, wqkvt, bqkv, Qb, Kb, Vtb, mask_len);
  attn_fwd<<<1056, 256, 0, stream>>>(Qb, Kb, Vtb, mask_len, Yb);
  gemm_out<<<dim3(8, 64), 256, 0, stream>>>(Yb, wot, bo, out);
}

// Round 20
// 90.681 us; speedup vs baseline: 1.0360x; 1.0135x over previous
//
#include <hip/hip_runtime.h>

typedef unsigned short u16;
typedef unsigned int u32;
typedef __bf16 bf16x8 __attribute__((ext_vector_type(8)));
typedef float f32x4 __attribute__((ext_vector_type(4)));
typedef u16 u16x2 __attribute__((ext_vector_type(2)));
typedef u16 u16x4 __attribute__((ext_vector_type(4)));
typedef u16 u16x8 __attribute__((ext_vector_type(8)));

#define LSEQ 2048
#define EMB  1024
#define NH   16
#define HDIM 64

// Q pre-scale: 1/sqrt(64) * log2(e)  (softmax computed in base 2)
#define QSCALE 0.1803368808f

#if __has_builtin(__builtin_amdgcn_exp2f)
#define EXP2(x) __builtin_amdgcn_exp2f(x)
#else
#define EXP2(x) __expf((x) * 0.6931471805599453f)
#endif

__device__ __forceinline__ u16 cvt_bf(float f) {
  __bf16 h = (__bf16)f;
  return __builtin_bit_cast(u16, h);
}
__device__ __forceinline__ float bf2f(u16 v) {
  return __uint_as_float(((unsigned)v) << 16);
}
__device__ __forceinline__ void async16(void* lds, const void* g) {
  __builtin_amdgcn_global_load_lds((const __attribute__((address_space(1))) void*)g,
                                   (__attribute__((address_space(3))) void*)lds, 16, 0, 0);
}
__device__ __forceinline__ f32x4 mfma16(bf16x8 a, bf16x8 b, f32x4 c) {
  return __builtin_amdgcn_mfma_f32_16x16x32_bf16(a, b, c, 0, 0, 0);
}

// ---------------- fused prep: x conversion + both weight transposes (R19) ----------------
__global__ void prep(const float* __restrict__ x, u16* __restrict__ xb,
                     const float* __restrict__ Wqkv, u16* __restrict__ WqkvT,
                     const float* __restrict__ Wo, u16* __restrict__ WoT) {
  __shared__ float tile[64][33];
  const int bid = blockIdx.x;
  const int tid = threadIdx.x;
  if (bid < 2048) {
    const int n4 = 1024 * 1024;
    for (int i = bid * 256 + tid; i < n4; i += 2048 * 256) {
      float4 v = ((const float4*)x)[i];
      u16x4 o = { cvt_bf(v.x), cvt_bf(v.y), cvt_bf(v.z), cvt_bf(v.w) };
      ((u16x4*)xb)[i] = o;
    }
    return;
  }
  const int idx = bid - 2048;          // 0..2047
  const int bx = idx & 127, by = idx >> 7;   // by 0..15
  const int Kd = 1024;
  const float* in;
  u16* out;
  int Nd, n0;
  if (bx < 96) { in = Wqkv; out = WqkvT; Nd = 3072; n0 = bx * 32; }
  else         { in = Wo;   out = WoT;   Nd = 1024; n0 = (bx - 96) * 32; }
  const int k0 = by * 64;
  const int tx = tid & 31, ty = tid >> 5;   // (32,8)
#pragma unroll
  for (int i = 0; i < 8; ++i)
    tile[ty + i * 8][tx] = in[(size_t)(k0 + ty + i * 8) * Nd + n0 + tx];
  __syncthreads();
#pragma unroll
  for (int i = 0; i < 4; ++i) {
    int nl = ty + i * 8;
    u16x2 v = { cvt_bf(tile[2 * tx][nl]), cvt_bf(tile[2 * tx + 1][nl]) };
    *(u16x2*)&out[(size_t)(n0 + nl) * Kd + k0 + 2 * tx] = v;
  }
}

// ---------------- QKV GEMM (R14 proven version: BN=128 head-pair typed blocks) ----------------
__launch_bounds__(256, 2)
__global__ void gemm_qkv(const u16* __restrict__ A, const u16* __restrict__ Bt,
                         const float* __restrict__ bias,
                         u16* __restrict__ Qo, u16* __restrict__ Ko, u16* __restrict__ Vo,
                         const int* __restrict__ mask_len) {
  __shared__ __attribute__((aligned(16))) u16 SMEM[4 * 8192];  // As[2][128*64] Bs[2][128*64]
  u16* As = SMEM;
  u16* Bs = SMEM + 2 * 8192;
  const int tid = threadIdx.x;
  const int w = tid >> 6, l = tid & 63;
  const int g = l >> 4, cc = l & 15;
  const int orig = blockIdx.y * 24 + blockIdx.x;
  const int wgid = (orig & 7) * 96 + (orig >> 3);   // XCD-bijective (768 % 8 == 0)
  const int m0 = (wgid / 24) * 128;
  const int tb = wgid % 24;
  const int type = tb >> 3, tbh = tb & 7;           // 0=Q 1=K 2=V; head pair 2*tbh+{0,1}
  const int bb = m0 >> 11;
  const int lo = mask_len[bb];
  if (type < 2 && (m0 & (LSEQ - 1)) >= lo) return;  // dead Q/K rows
  const int wm = w >> 1, wn = w & 1;
  const int K = 1024;

  const int srow8 = tid >> 3;       // 0..31 row within call
  const int chunk = tid & 7;
  auto stage = [&](int buf, int k0) {
#pragma unroll
    for (int c = 0; c < 4; ++c) {
      int R = c * 32 + srow8;                 // 0..127 panel row
      int col = (chunk ^ (R & 7)) * 8;        // pre-swizzled source (elems)
      async16((char*)&As[buf * 8192] + c * 4096 + w * 1024,
              A + (size_t)(m0 + R) * K + k0 + col);
      int gR = (2 * tbh + (R >> 6)) * 192 + type * 64 + (R & 63);
      async16((char*)&Bs[buf * 8192] + c * 4096 + w * 1024,
              Bt + (size_t)gR * K + k0 + col);
    }
  };

  f32x4 acc[4][4] = {};
  stage(0, 0);
  for (int t = 0; t < 16; ++t) {
    const int cur = t & 1;
    if (t + 1 < 16) {
      stage(cur ^ 1, (t + 1) * 64);
      asm volatile("s_waitcnt vmcnt(8)" ::: "memory");
    } else {
      asm volatile("s_waitcnt vmcnt(0)" ::: "memory");
    }
    __builtin_amdgcn_s_barrier();
    __builtin_amdgcn_sched_barrier(0);
    const char* AB = (const char*)&As[cur * 8192];
    const char* BB = (const char*)&Bs[cur * 8192];
#pragma unroll
    for (int ks = 0; ks < 2; ++ks) {
      bf16x8 af[4], bfr[4];
#pragma unroll
      for (int mf = 0; mf < 4; ++mf) {
        int row = wm * 64 + mf * 16 + cc;
        af[mf] = *(const bf16x8*)(AB + row * 128 + ((ks * 64 + g * 16) ^ ((row & 7) << 4)));
      }
#pragma unroll
      for (int nf = 0; nf < 4; ++nf) {
        int row = wn * 64 + nf * 16 + cc;
        bfr[nf] = *(const bf16x8*)(BB + row * 128 + ((ks * 64 + g * 16) ^ ((row & 7) << 4)));
      }
#pragma unroll
      for (int mf = 0; mf < 4; ++mf)
#pragma unroll
        for (int nf = 0; nf < 4; ++nf)
          acc[mf][nf] = mfma16(af[mf], bfr[nf], acc[mf][nf]);
    }
    __builtin_amdgcn_s_barrier();
  }

  __syncthreads();
  {
    char* P = (char*)SMEM + wn * 16384;
    const float* bptr = bias + (2 * tbh + wn) * 192 + type * 64;
#pragma unroll
    for (int mf = 0; mf < 4; ++mf) {
#pragma unroll
      for (int nf = 0; nf < 4; ++nf) {
        int d = nf * 16 + cc;
        float bv = bptr[d];
#pragma unroll
        for (int r = 0; r < 4; ++r) {
          int ml = wm * 64 + mf * 16 + g * 4 + r;
          float val = acc[mf][nf][r] + bv;
          if (type == 0) val *= QSCALE;
          u16 hv = cvt_bf(val);
          if (type == 2) *(u16*)(P + d * 256 + ((ml * 2) ^ ((d & 7) << 5))) = hv;
          else           *(u16*)(P + ml * 128 + ((d * 2) ^ (((ml >> 2) & 3) << 5))) = hv;
        }
      }
    }
  }
  __syncthreads();
  const int ls0 = m0 & (LSEQ - 1);
#pragma unroll
  for (int wi = 0; wi < 2; ++wi) {
    const int bh = bb * NH + 2 * tbh + wi;
    char* P = (char*)SMEM + wi * 16384;
    if (type == 2) {
      u16* dstb = Vo + (size_t)bh * HDIM * LSEQ + ls0;
#pragma unroll
      for (int it = 0; it < 4; ++it) {
        int idx = it * 256 + tid;
        int row = idx >> 4;
        int colB = (idx & 15) * 16;
        int4 v = *(const int4*)(P + row * 256 + (colB ^ ((row & 7) << 5)));
        *(int4*)((char*)(dstb + (size_t)row * LSEQ) + colB) = v;
      }
    } else {
      u16* dst = (type == 0 ? Qo : Ko) + ((size_t)bh * LSEQ + ls0) * HDIM;
#pragma unroll
      for (int it = 0; it < 4; ++it) {
        int idx = it * 256 + tid;
        int row = idx >> 3;
        int colB = (idx & 7) * 16;
        int4 v = *(const int4*)(P + row * 128 + (colB ^ (((row >> 2) & 3) << 5)));
        *(int4*)((char*)dst + row * 128 + colB) = v;
      }
    }
  }
}

// ---------------- out-proj GEMM (R17, unchanged) ----------------
__launch_bounds__(256, 2)
__global__ void gemm_out(const u16* __restrict__ A, const u16* __restrict__ Bt,
                         const float* __restrict__ bias, float* __restrict__ Out) {
  __shared__ __attribute__((aligned(16))) u16 SMEM[2 * 4096 + 2 * 8192];
  u16* As = SMEM;                    // [2][64*64]
  u16* Bs = SMEM + 2 * 4096;         // [2][128*64]
  const int tid = threadIdx.x;
  const int w = tid >> 6, l = tid & 63;
  const int g = l >> 4, cc = l & 15;
  const int orig = blockIdx.y * 8 + blockIdx.x;
  const int wgid = (orig & 7) * 64 + (orig >> 3);   // XCD-bijective (512 % 8 == 0)
  const int m0 = (wgid >> 3) * 64;
  const int n0 = (wgid & 7) * 128;
  const int wm = w >> 1, wn = w & 1;
  const int K = 1024;
  const int srow8 = tid >> 3;       // 0..31 row within call
  const int chunk = tid & 7;

  auto stage = [&](int buf, int k0) {
#pragma unroll
    for (int c = 0; c < 2; ++c) {
      int R = c * 32 + srow8;                 // 0..63 A-panel row
      int col = (chunk ^ (R & 7)) * 8;        // pre-swizzled source (elems)
      async16((char*)As + buf * 8192 + c * 4096 + w * 1024,
              A + (size_t)(m0 + R) * K + k0 + col);
    }
#pragma unroll
    for (int c = 0; c < 4; ++c) {
      int R = c * 32 + srow8;                 // 0..127 B-panel row
      int col = (chunk ^ (R & 7)) * 8;
      async16((char*)Bs + buf * 16384 + c * 4096 + w * 1024,
              Bt + (size_t)(n0 + R) * K + k0 + col);
    }
  };

  f32x4 acc[2][4] = {};
  stage(0, 0);
  for (int t = 0; t < 16; ++t) {
    const int cur = t & 1;
    if (t + 1 < 16) {
      stage(cur ^ 1, (t + 1) * 64);
      asm volatile("s_waitcnt vmcnt(6)" ::: "memory");  // this tile done; next 6 in flight
    } else {
      asm volatile("s_waitcnt vmcnt(0)" ::: "memory");
    }
    __builtin_amdgcn_s_barrier();
    __builtin_amdgcn_sched_barrier(0);
    const char* AB = (const char*)As + cur * 8192;
    const char* BB = (const char*)Bs + cur * 16384;
#pragma unroll
    for (int ks = 0; ks < 2; ++ks) {
      bf16x8 af[2], bfr[4];
#pragma unroll
      for (int mf = 0; mf < 2; ++mf) {
        int row = wm * 32 + mf * 16 + cc;
        af[mf] = *(const bf16x8*)(AB + row * 128 + ((ks * 64 + g * 16) ^ ((row & 7) << 4)));
      }
#pragma unroll
      for (int nf = 0; nf < 4; ++nf) {
        int row = wn * 64 + nf * 16 + cc;
        bfr[nf] = *(const bf16x8*)(BB + row * 128 + ((ks * 64 + g * 16) ^ ((row & 7) << 4)));
      }
#pragma unroll
      for (int mf = 0; mf < 2; ++mf)
#pragma unroll
        for (int nf = 0; nf < 4; ++nf)
          acc[mf][nf] = mfma16(af[mf], bfr[nf], acc[mf][nf]);
    }
    __builtin_amdgcn_s_barrier();   // WAR guard; no vmcnt drain
  }

  // epilogue: direct fp32 stores + bias
#pragma unroll
  for (int mf = 0; mf < 2; ++mf) {
#pragma unroll
    for (int nf = 0; nf < 4; ++nf) {
      int n = n0 + wn * 64 + nf * 16 + cc;
      float bv = bias[n];
#pragma unroll
      for (int r = 0; r < 4; ++r) {
        int m = m0 + wm * 32 + mf * 16 + g * 4 + r;
        Out[(size_t)m * EMB + n] = acc[mf][nf][r] + bv;
      }
    }
  }
}

// ---------------- flash attention, R20: meanv folded into k==8 blocks ----------------
// Grid exactly 1024 (one clean 4/CU co-residency wave). The 32 blocks with
// k==8 (qblk=0, nt=1 -- lightest; never mask-skipped since lo >= 1) run the
// meanv fill for their bh AFTER their single attn tile: meanv work now
// overlaps the heavy qblk=31 stragglers instead of queuing behind the grid.
__launch_bounds__(256)
__global__ void attn_fwd(const u16* __restrict__ Q, const u16* __restrict__ Kb,
                         const u16* __restrict__ Vt, const int* __restrict__ mask_len,
                         u16* __restrict__ Y) {
  __shared__ __attribute__((aligned(16))) u16 Ks[2][64 * 64];
  __shared__ __attribute__((aligned(16))) u16 Vs[2][64 * 64];
  __shared__ __attribute__((aligned(16))) u16 Ps[4 * 16 * 64];
  const int tid = threadIdx.x;
  const int i = blockIdx.x;

  const int w = tid >> 6, l = tid & 63;
  const int g = l >> 4, cc = l & 15;
  const int bh = i & 31;
  const int k = i >> 5, grp = k >> 3, j = k & 7;
  int qblk;
  if (grp == 0) qblk = 31 - j;
  else if (grp == 1) qblk = j;
  else if (grp == 2) qblk = 23 - j;
  else qblk = 8 + j;
  const int q0 = qblk * 64;
  const int nt = qblk + 1;
  const int b = bh >> 4, h = bh & (NH - 1);

  const int lo = mask_len[b];
  const bool carrier = (k == 8);           // qblk==0: always live (lo >= 1)
  if (!carrier && q0 >= lo) return;

  if (q0 < lo) {
    const int sr = w * 8 + (l >> 3);
    const int pb = (l & 7) * 16;
    char* Pw = (char*)&Ps[w * 16 * 64];
    const int xc = (cc & 7) << 4;

    auto stageKV = [&](int buf, int t) {
      const int kv0 = t * 64;
#pragma unroll
      for (int ch = 0; ch < 2; ++ch) {
        int R = sr + ch * 32;
        int dcol = (pb ^ ((R & 7) << 4)) >> 1;
        async16((char*)Ks[buf] + ch * 4096 + w * 1024,
                Kb + ((size_t)bh * LSEQ + kv0 + R) * HDIM + dcol);
        async16((char*)Vs[buf] + ch * 4096 + w * 1024,
                Vt + ((size_t)bh * HDIM + R) * LSEQ + kv0 + dcol);
      }
    };

    const u16* Qg = Q + ((size_t)bh * LSEQ + q0 + w * 16) * HDIM;
    bf16x8 qf0 = *(const bf16x8*)&Qg[cc * HDIM + g * 8];
    bf16x8 qf1 = *(const bf16x8*)&Qg[cc * HDIM + 32 + g * 8];

    bf16x8 onesf;
#pragma unroll
    for (int z = 0; z < 8; ++z) onesf[z] = (__bf16)1.0f;

    f32x4 o[4] = {};
    f32x4 ls = {};

    stageKV(0, 0);

    for (int t = 0; t < nt; ++t) {
      const int cur = t & 1;
      if (t + 1 < nt) {
        stageKV(cur ^ 1, t + 1);
        asm volatile("s_waitcnt vmcnt(4)" ::: "memory");
      } else {
        asm volatile("s_waitcnt vmcnt(0)" ::: "memory");
      }
      __builtin_amdgcn_s_barrier();
      __builtin_amdgcn_sched_barrier(0);
      const char* KsB = (const char*)Ks[cur];
      const char* VsB = (const char*)Vs[cur];

      f32x4 sf[4] = {};
      __builtin_amdgcn_s_setprio(1);
#pragma unroll
      for (int nf = 0; nf < 4; ++nf) {
        bf16x8 kf0 = *(const bf16x8*)(KsB + (nf * 16 + cc) * 128 + ((g * 16) ^ xc));
        bf16x8 kf1 = *(const bf16x8*)(KsB + (nf * 16 + cc) * 128 + ((64 + g * 16) ^ xc));
        sf[nf] = mfma16(qf0, kf0, sf[nf]);
        sf[nf] = mfma16(qf1, kf1, sf[nf]);
      }
      __builtin_amdgcn_s_setprio(0);

      if (t == nt - 1) {  // diagonal tile: causal mask
#pragma unroll
        for (int nf = 0; nf < 4; ++nf) {
          int kvl = nf * 16 + cc;
#pragma unroll
          for (int r = 0; r < 4; ++r)
            if (kvl > w * 16 + g * 4 + r) sf[nf][r] = -1e30f;
        }
      }

#pragma unroll
      for (int r = 0; r < 4; ++r) {
        int q = g * 4 + r;
        int xr = (q & 7) << 4;
#pragma unroll
        for (int nf = 0; nf < 4; ++nf) {
          float pv = EXP2(sf[nf][r]);
          *(u16*)(Pw + q * 128 + (((nf * 16 + cc) * 2) ^ xr)) = cvt_bf(pv);
        }
      }
      asm volatile("s_waitcnt lgkmcnt(0)" ::: "memory");
      __builtin_amdgcn_sched_barrier(0);

      bf16x8 pf0 = *(const bf16x8*)(Pw + cc * 128 + ((g * 16) ^ xc));
      bf16x8 pf1 = *(const bf16x8*)(Pw + cc * 128 + ((64 + g * 16) ^ xc));
      __builtin_amdgcn_s_setprio(1);
      ls = mfma16(pf1, onesf, mfma16(pf0, onesf, ls));
#pragma unroll
      for (int nf = 0; nf < 4; ++nf) {
        bf16x8 vf0 = *(const bf16x8*)(VsB + (nf * 16 + cc) * 128 + ((g * 16) ^ xc));
        bf16x8 vf1 = *(const bf16x8*)(VsB + (nf * 16 + cc) * 128 + ((64 + g * 16) ^ xc));
        o[nf] = mfma16(pf0, vf0, o[nf]);
        o[nf] = mfma16(pf1, vf1, o[nf]);
      }
      __builtin_amdgcn_s_setprio(0);
      __builtin_amdgcn_s_barrier();   // WAR guard; no vmcnt drain
    }

#pragma unroll
    for (int r = 0; r < 4; ++r) {
      int row = q0 + w * 16 + g * 4 + r;
      if (row < lo) {
        float inv = 1.0f / ls[r];
        size_t base = ((size_t)b * LSEQ + row) * EMB + h * HDIM;
#pragma unroll
        for (int nf = 0; nf < 4; ++nf)
          Y[base + nf * 16 + cc] = cvt_bf(o[nf][r] * inv);
      }
    }
  }

  if (carrier) {
    // ---- meanv fill for this bh: Y[b, row>=lo, h*64+d] = mean_kv V ----
    __syncthreads();                 // all waves past attn LDS use
    float* partial = (float*)Ks;
    u16* mv = (u16*)((char*)Ks + 1024);
    int d = tid >> 2, part = tid & 3;
    const u16* src = Vt + ((size_t)bh * HDIM + d) * LSEQ + part * 512;
    float s = 0.f;
    for (int ii = 0; ii < 512; ii += 8) {
      u16x8 v = *(const u16x8*)&src[ii];
#pragma unroll
      for (int jj = 0; jj < 8; ++jj) s += bf2f(v[jj]);
    }
    partial[tid] = s;
    __syncthreads();
    if (part == 0) {
      float t = partial[tid] + partial[tid + 1] + partial[tid + 2] + partial[tid + 3];
      mv[d] = cvt_bf(t * (1.0f / (float)LSEQ));
    }
    __syncthreads();
    int lof = lo;
    if (lof < 0) lof = 0;
    if (lof > LSEQ) lof = LSEQ;
    int total = (LSEQ - lof) * HDIM;
    for (int idx = tid; idx < total; idx += 256) {
      int row = lof + (idx >> 6), dd = idx & 63;
      Y[((size_t)b * LSEQ + row) * EMB + h * HDIM + dd] = mv[dd];
    }
  }
}

// ---------------- launch ----------------
extern "C" void kernel_launch(void* const* d_in, const int* in_sizes, int n_in,
                              void* d_out, int out_size, void* d_ws, size_t ws_size,
                              hipStream_t stream) {
  (void)in_sizes; (void)n_in; (void)out_size; (void)ws_size;
  const float* x    = (const float*)d_in[0];
  const float* Wqkv = (const float*)d_in[1];
  const float* bqkv = (const float*)d_in[2];
  const float* Wo   = (const float*)d_in[3];
  const float* bo   = (const float*)d_in[4];
  const int* mask_len = (const int*)d_in[5];
  float* out = (float*)d_out;

  u16* ws = (u16*)d_ws;
  u16* xb    = ws;                              // 4M elems (x bf16) — reused as Y later
  u16* wqkvt = ws + (size_t)4 * 1024 * 1024;    // 3M (W_qkv^T bf16)
  u16* wot   = wqkvt + (size_t)3 * 1024 * 1024; // 1M (W_o^T bf16)
  u16* Qb    = wot + (size_t)1024 * 1024;       // 4M
  u16* Kb    = Qb + (size_t)4 * 1024 * 1024;    // 4M
  u16* Vtb   = Kb + (size_t)4 * 1024 * 1024;    // 4M
  u16* Yb    = xb;                              // alias: x dead after gemm_qkv

  prep<<<4096, 256, 0, stream>>>(x, xb, Wqkv, wqkvt, Wo, wot);
  gemm_qkv<<<dim3(24, 32), 256, 0, stream>>>(xb, wqkvt, bqkv, Qb, Kb, Vtb, mask_len);
  attn_fwd<<<1024, 256, 0, stream>>>(Qb, Kb, Vtb, mask_len, Yb);
  gemm_out<<<dim3(8, 64), 256, 0, stream>>>(Yb, wot, bo, out);
}

// Round 21
// 90.648 us; speedup vs baseline: 1.0364x; 1.0004x over previous
//
#include <hip/hip_runtime.h>

typedef unsigned short u16;
typedef unsigned int u32;
typedef __bf16 bf16x8 __attribute__((ext_vector_type(8)));
typedef float f32x4 __attribute__((ext_vector_type(4)));
typedef u16 u16x2 __attribute__((ext_vector_type(2)));
typedef u16 u16x4 __attribute__((ext_vector_type(4)));
typedef u16 u16x8 __attribute__((ext_vector_type(8)));

#define LSEQ 2048
#define EMB  1024
#define NH   16
#define HDIM 64

// Q pre-scale: 1/sqrt(64) * log2(e)  (softmax computed in base 2)
#define QSCALE 0.1803368808f

#if __has_builtin(__builtin_amdgcn_exp2f)
#define EXP2(x) __builtin_amdgcn_exp2f(x)
#else
#define EXP2(x) __expf((x) * 0.6931471805599453f)
#endif

__device__ __forceinline__ u16 cvt_bf(float f) {
  __bf16 h = (__bf16)f;
  return __builtin_bit_cast(u16, h);
}
__device__ __forceinline__ float bf2f(u16 v) {
  return __uint_as_float(((unsigned)v) << 16);
}
__device__ __forceinline__ void async16(void* lds, const void* g) {
  __builtin_amdgcn_global_load_lds((const __attribute__((address_space(1))) void*)g,
                                   (__attribute__((address_space(3))) void*)lds, 16, 0, 0);
}
__device__ __forceinline__ f32x4 mfma16(bf16x8 a, bf16x8 b, f32x4 c) {
  return __builtin_amdgcn_mfma_f32_16x16x32_bf16(a, b, c, 0, 0, 0);
}

// ---------------- fused prep: x conversion + both weight transposes ----------------
__global__ void prep(const float* __restrict__ x, u16* __restrict__ xb,
                     const float* __restrict__ Wqkv, u16* __restrict__ WqkvT,
                     const float* __restrict__ Wo, u16* __restrict__ WoT) {
  __shared__ float tile[64][33];
  const int bid = blockIdx.x;
  const int tid = threadIdx.x;
  if (bid < 2048) {
    const int n4 = 1024 * 1024;
    for (int i = bid * 256 + tid; i < n4; i += 2048 * 256) {
      float4 v = ((const float4*)x)[i];
      u16x4 o = { cvt_bf(v.x), cvt_bf(v.y), cvt_bf(v.z), cvt_bf(v.w) };
      ((u16x4*)xb)[i] = o;
    }
    return;
  }
  const int idx = bid - 2048;          // 0..2047
  const int bx = idx & 127, by = idx >> 7;   // by 0..15
  const int Kd = 1024;
  const float* in;
  u16* out;
  int Nd, n0;
  if (bx < 96) { in = Wqkv; out = WqkvT; Nd = 3072; n0 = bx * 32; }
  else         { in = Wo;   out = WoT;   Nd = 1024; n0 = (bx - 96) * 32; }
  const int k0 = by * 64;
  const int tx = tid & 31, ty = tid >> 5;   // (32,8)
#pragma unroll
  for (int i = 0; i < 8; ++i)
    tile[ty + i * 8][tx] = in[(size_t)(k0 + ty + i * 8) * Nd + n0 + tx];
  __syncthreads();
#pragma unroll
  for (int i = 0; i < 4; ++i) {
    int nl = ty + i * 8;
    u16x2 v = { cvt_bf(tile[2 * tx][nl]), cvt_bf(tile[2 * tx + 1][nl]) };
    *(u16x2*)&out[(size_t)(n0 + nl) * Kd + k0 + 2 * tx] = v;
  }
}

// ---------------- QKV GEMM (BN=128 head-pair typed blocks; BK=64 + XOR-16) ----------------
__launch_bounds__(256, 2)
__global__ void gemm_qkv(const u16* __restrict__ A, const u16* __restrict__ Bt,
                         const float* __restrict__ bias,
                         u16* __restrict__ Qo, u16* __restrict__ Ko, u16* __restrict__ Vo,
                         const int* __restrict__ mask_len) {
  __shared__ __attribute__((aligned(16))) u16 SMEM[4 * 8192];  // As[2][128*64] Bs[2][128*64]
  u16* As = SMEM;
  u16* Bs = SMEM + 2 * 8192;
  const int tid = threadIdx.x;
  const int w = tid >> 6, l = tid & 63;
  const int g = l >> 4, cc = l & 15;
  const int orig = blockIdx.y * 24 + blockIdx.x;
  const int wgid = (orig & 7) * 96 + (orig >> 3);   // XCD-bijective (768 % 8 == 0)
  const int m0 = (wgid / 24) * 128;
  const int tb = wgid % 24;
  const int type = tb >> 3, tbh = tb & 7;           // 0=Q 1=K 2=V; head pair 2*tbh+{0,1}
  const int bb = m0 >> 11;
  const int lo = mask_len[bb];
  if (type < 2 && (m0 & (LSEQ - 1)) >= lo) return;  // dead Q/K rows
  const int wm = w >> 1, wn = w & 1;
  const int K = 1024;

  const int srow8 = tid >> 3;       // 0..31 row within call
  const int chunk = tid & 7;
  auto stage = [&](int buf, int k0) {
#pragma unroll
    for (int c = 0; c < 4; ++c) {
      int R = c * 32 + srow8;                 // 0..127 panel row
      int col = (chunk ^ (R & 7)) * 8;        // pre-swizzled source (elems)
      async16((char*)&As[buf * 8192] + c * 4096 + w * 1024,
              A + (size_t)(m0 + R) * K + k0 + col);
      int gR = (2 * tbh + (R >> 6)) * 192 + type * 64 + (R & 63);
      async16((char*)&Bs[buf * 8192] + c * 4096 + w * 1024,
              Bt + (size_t)gR * K + k0 + col);
    }
  };

  f32x4 acc[4][4] = {};
  stage(0, 0);
  for (int t = 0; t < 16; ++t) {
    const int cur = t & 1;
    if (t + 1 < 16) {
      stage(cur ^ 1, (t + 1) * 64);
      asm volatile("s_waitcnt vmcnt(8)" ::: "memory");
    } else {
      asm volatile("s_waitcnt vmcnt(0)" ::: "memory");
    }
    __builtin_amdgcn_s_barrier();
    __builtin_amdgcn_sched_barrier(0);
    const char* AB = (const char*)&As[cur * 8192];
    const char* BB = (const char*)&Bs[cur * 8192];
#pragma unroll
    for (int ks = 0; ks < 2; ++ks) {
      bf16x8 af[4], bfr[4];
#pragma unroll
      for (int mf = 0; mf < 4; ++mf) {
        int row = wm * 64 + mf * 16 + cc;
        af[mf] = *(const bf16x8*)(AB + row * 128 + ((ks * 64 + g * 16) ^ ((row & 7) << 4)));
      }
#pragma unroll
      for (int nf = 0; nf < 4; ++nf) {
        int row = wn * 64 + nf * 16 + cc;
        bfr[nf] = *(const bf16x8*)(BB + row * 128 + ((ks * 64 + g * 16) ^ ((row & 7) << 4)));
      }
#pragma unroll
      for (int mf = 0; mf < 4; ++mf)
#pragma unroll
        for (int nf = 0; nf < 4; ++nf)
          acc[mf][nf] = mfma16(af[mf], bfr[nf], acc[mf][nf]);
    }
    __builtin_amdgcn_s_barrier();
  }

  __syncthreads();
  {
    char* P = (char*)SMEM + wn * 16384;
    const float* bptr = bias + (2 * tbh + wn) * 192 + type * 64;
#pragma unroll
    for (int mf = 0; mf < 4; ++mf) {
#pragma unroll
      for (int nf = 0; nf < 4; ++nf) {
        int d = nf * 16 + cc;
        float bv = bptr[d];
#pragma unroll
        for (int r = 0; r < 4; ++r) {
          int ml = wm * 64 + mf * 16 + g * 4 + r;
          float val = acc[mf][nf][r] + bv;
          if (type == 0) val *= QSCALE;
          u16 hv = cvt_bf(val);
          if (type == 2) *(u16*)(P + d * 256 + ((ml * 2) ^ ((d & 7) << 5))) = hv;
          else           *(u16*)(P + ml * 128 + ((d * 2) ^ (((ml >> 2) & 3) << 5))) = hv;
        }
      }
    }
  }
  __syncthreads();
  const int ls0 = m0 & (LSEQ - 1);
#pragma unroll
  for (int wi = 0; wi < 2; ++wi) {
    const int bh = bb * NH + 2 * tbh + wi;
    char* P = (char*)SMEM + wi * 16384;
    if (type == 2) {
      u16* dstb = Vo + (size_t)bh * HDIM * LSEQ + ls0;
#pragma unroll
      for (int it = 0; it < 4; ++it) {
        int idx = it * 256 + tid;
        int row = idx >> 4;
        int colB = (idx & 15) * 16;
        int4 v = *(const int4*)(P + row * 256 + (colB ^ ((row & 7) << 5)));
        *(int4*)((char*)(dstb + (size_t)row * LSEQ) + colB) = v;
      }
    } else {
      u16* dst = (type == 0 ? Qo : Ko) + ((size_t)bh * LSEQ + ls0) * HDIM;
#pragma unroll
      for (int it = 0; it < 4; ++it) {
        int idx = it * 256 + tid;
        int row = idx >> 3;
        int colB = (idx & 7) * 16;
        int4 v = *(const int4*)(P + row * 128 + (colB ^ (((row >> 2) & 3) << 5)));
        *(int4*)((char*)dst + row * 128 + colB) = v;
      }
    }
  }
}

// ---------------- out-proj GEMM (BK=64 + XOR-16, conflict-free frags) ----------------
__launch_bounds__(256, 2)
__global__ void gemm_out(const u16* __restrict__ A, const u16* __restrict__ Bt,
                         const float* __restrict__ bias, float* __restrict__ Out) {
  __shared__ __attribute__((aligned(16))) u16 SMEM[2 * 4096 + 2 * 8192];
  u16* As = SMEM;                    // [2][64*64]
  u16* Bs = SMEM + 2 * 4096;         // [2][128*64]
  const int tid = threadIdx.x;
  const int w = tid >> 6, l = tid & 63;
  const int g = l >> 4, cc = l & 15;
  const int orig = blockIdx.y * 8 + blockIdx.x;
  const int wgid = (orig & 7) * 64 + (orig >> 3);   // XCD-bijective (512 % 8 == 0)
  const int m0 = (wgid >> 3) * 64;
  const int n0 = (wgid & 7) * 128;
  const int wm = w >> 1, wn = w & 1;
  const int K = 1024;
  const int srow8 = tid >> 3;       // 0..31 row within call
  const int chunk = tid & 7;

  auto stage = [&](int buf, int k0) {
#pragma unroll
    for (int c = 0; c < 2; ++c) {
      int R = c * 32 + srow8;                 // 0..63 A-panel row
      int col = (chunk ^ (R & 7)) * 8;        // pre-swizzled source (elems)
      async16((char*)As + buf * 8192 + c * 4096 + w * 1024,
              A + (size_t)(m0 + R) * K + k0 + col);
    }
#pragma unroll
    for (int c = 0; c < 4; ++c) {
      int R = c * 32 + srow8;                 // 0..127 B-panel row
      int col = (chunk ^ (R & 7)) * 8;
      async16((char*)Bs + buf * 16384 + c * 4096 + w * 1024,
              Bt + (size_t)(n0 + R) * K + k0 + col);
    }
  };

  f32x4 acc[2][4] = {};
  stage(0, 0);
  for (int t = 0; t < 16; ++t) {
    const int cur = t & 1;
    if (t + 1 < 16) {
      stage(cur ^ 1, (t + 1) * 64);
      asm volatile("s_waitcnt vmcnt(6)" ::: "memory");  // this tile done; next 6 in flight
    } else {
      asm volatile("s_waitcnt vmcnt(0)" ::: "memory");
    }
    __builtin_amdgcn_s_barrier();
    __builtin_amdgcn_sched_barrier(0);
    const char* AB = (const char*)As + cur * 8192;
    const char* BB = (const char*)Bs + cur * 16384;
#pragma unroll
    for (int ks = 0; ks < 2; ++ks) {
      bf16x8 af[2], bfr[4];
#pragma unroll
      for (int mf = 0; mf < 2; ++mf) {
        int row = wm * 32 + mf * 16 + cc;
        af[mf] = *(const bf16x8*)(AB + row * 128 + ((ks * 64 + g * 16) ^ ((row & 7) << 4)));
      }
#pragma unroll
      for (int nf = 0; nf < 4; ++nf) {
        int row = wn * 64 + nf * 16 + cc;
        bfr[nf] = *(const bf16x8*)(BB + row * 128 + ((ks * 64 + g * 16) ^ ((row & 7) << 4)));
      }
#pragma unroll
      for (int mf = 0; mf < 2; ++mf)
#pragma unroll
        for (int nf = 0; nf < 4; ++nf)
          acc[mf][nf] = mfma16(af[mf], bfr[nf], acc[mf][nf]);
    }
    __builtin_amdgcn_s_barrier();   // WAR guard; no vmcnt drain
  }

  // epilogue: direct fp32 stores + bias
#pragma unroll
  for (int mf = 0; mf < 2; ++mf) {
#pragma unroll
    for (int nf = 0; nf < 4; ++nf) {
      int n = n0 + wn * 64 + nf * 16 + cc;
      float bv = bias[n];
#pragma unroll
      for (int r = 0; r < 4; ++r) {
        int m = m0 + wm * 32 + mf * 16 + g * 4 + r;
        Out[(size_t)m * EMB + n] = acc[mf][nf][r] + bv;
      }
    }
  }
}

// ---------------- flash attention: meanv folded into k==8 blocks ----------------
__launch_bounds__(256)
__global__ void attn_fwd(const u16* __restrict__ Q, const u16* __restrict__ Kb,
                         const u16* __restrict__ Vt, const int* __restrict__ mask_len,
                         u16* __restrict__ Y) {
  __shared__ __attribute__((aligned(16))) u16 Ks[2][64 * 64];
  __shared__ __attribute__((aligned(16))) u16 Vs[2][64 * 64];
  __shared__ __attribute__((aligned(16))) u16 Ps[4 * 16 * 64];
  const int tid = threadIdx.x;
  const int i = blockIdx.x;

  const int w = tid >> 6, l = tid & 63;
  const int g = l >> 4, cc = l & 15;
  const int bh = i & 31;
  const int k = i >> 5, grp = k >> 3, j = k & 7;
  int qblk;
  if (grp == 0) qblk = 31 - j;
  else if (grp == 1) qblk = j;
  else if (grp == 2) qblk = 23 - j;
  else qblk = 8 + j;
  const int q0 = qblk * 64;
  const int nt = qblk + 1;
  const int b = bh >> 4, h = bh & (NH - 1);

  const int lo = mask_len[b];
  const bool carrier = (k == 8);           // qblk==0: always live (lo >= 1)
  if (!carrier && q0 >= lo) return;

  if (q0 < lo) {
    const int sr = w * 8 + (l >> 3);
    const int pb = (l & 7) * 16;
    char* Pw = (char*)&Ps[w * 16 * 64];
    const int xc = (cc & 7) << 4;

    auto stageKV = [&](int buf, int t) {
      const int kv0 = t * 64;
#pragma unroll
      for (int ch = 0; ch < 2; ++ch) {
        int R = sr + ch * 32;
        int dcol = (pb ^ ((R & 7) << 4)) >> 1;
        async16((char*)Ks[buf] + ch * 4096 + w * 1024,
                Kb + ((size_t)bh * LSEQ + kv0 + R) * HDIM + dcol);
        async16((char*)Vs[buf] + ch * 4096 + w * 1024,
                Vt + ((size_t)bh * HDIM + R) * LSEQ + kv0 + dcol);
      }
    };

    const u16* Qg = Q + ((size_t)bh * LSEQ + q0 + w * 16) * HDIM;
    bf16x8 qf0 = *(const bf16x8*)&Qg[cc * HDIM + g * 8];
    bf16x8 qf1 = *(const bf16x8*)&Qg[cc * HDIM + 32 + g * 8];

    bf16x8 onesf;
#pragma unroll
    for (int z = 0; z < 8; ++z) onesf[z] = (__bf16)1.0f;

    f32x4 o[4] = {};
    f32x4 ls = {};

    stageKV(0, 0);

    for (int t = 0; t < nt; ++t) {
      const int cur = t & 1;
      if (t + 1 < nt) {
        stageKV(cur ^ 1, t + 1);
        asm volatile("s_waitcnt vmcnt(4)" ::: "memory");
      } else {
        asm volatile("s_waitcnt vmcnt(0)" ::: "memory");
      }
      __builtin_amdgcn_s_barrier();
      __builtin_amdgcn_sched_barrier(0);
      const char* KsB = (const char*)Ks[cur];
      const char* VsB = (const char*)Vs[cur];

      f32x4 sf[4] = {};
      __builtin_amdgcn_s_setprio(1);
#pragma unroll
      for (int nf = 0; nf < 4; ++nf) {
        bf16x8 kf0 = *(const bf16x8*)(KsB + (nf * 16 + cc) * 128 + ((g * 16) ^ xc));
        bf16x8 kf1 = *(const bf16x8*)(KsB + (nf * 16 + cc) * 128 + ((64 + g * 16) ^ xc));
        sf[nf] = mfma16(qf0, kf0, sf[nf]);
        sf[nf] = mfma16(qf1, kf1, sf[nf]);
      }
      __builtin_amdgcn_s_setprio(0);

      if (t == nt - 1) {  // diagonal tile: causal mask
#pragma unroll
        for (int nf = 0; nf < 4; ++nf) {
          int kvl = nf * 16 + cc;
#pragma unroll
          for (int r = 0; r < 4; ++r)
            if (kvl > w * 16 + g * 4 + r) sf[nf][r] = -1e30f;
        }
      }

#pragma unroll
      for (int r = 0; r < 4; ++r) {
        int q = g * 4 + r;
        int xr = (q & 7) << 4;
#pragma unroll
        for (int nf = 0; nf < 4; ++nf) {
          float pv = EXP2(sf[nf][r]);
          *(u16*)(Pw + q * 128 + (((nf * 16 + cc) * 2) ^ xr)) = cvt_bf(pv);
        }
      }
      asm volatile("s_waitcnt lgkmcnt(0)" ::: "memory");
      __builtin_amdgcn_sched_barrier(0);

      bf16x8 pf0 = *(const bf16x8*)(Pw + cc * 128 + ((g * 16) ^ xc));
      bf16x8 pf1 = *(const bf16x8*)(Pw + cc * 128 + ((64 + g * 16) ^ xc));
      __builtin_amdgcn_s_setprio(1);
      ls = mfma16(pf1, onesf, mfma16(pf0, onesf, ls));
#pragma unroll
      for (int nf = 0; nf < 4; ++nf) {
        bf16x8 vf0 = *(const bf16x8*)(VsB + (nf * 16 + cc) * 128 + ((g * 16) ^ xc));
        bf16x8 vf1 = *(const bf16x8*)(VsB + (nf * 16 + cc) * 128 + ((64 + g * 16) ^ xc));
        o[nf] = mfma16(pf0, vf0, o[nf]);
        o[nf] = mfma16(pf1, vf1, o[nf]);
      }
      __builtin_amdgcn_s_setprio(0);
      __builtin_amdgcn_s_barrier();   // WAR guard; no vmcnt drain
    }

#pragma unroll
    for (int r = 0; r < 4; ++r) {
      int row = q0 + w * 16 + g * 4 + r;
      if (row < lo) {
        float inv = 1.0f / ls[r];
        size_t base = ((size_t)b * LSEQ + row) * EMB + h * HDIM;
#pragma unroll
        for (int nf = 0; nf < 4; ++nf)
          Y[base + nf * 16 + cc] = cvt_bf(o[nf][r] * inv);
      }
    }
  }

  if (carrier) {
    // ---- meanv fill for this bh: Y[b, row>=lo, h*64+d] = mean_kv V ----
    __syncthreads();                 // all waves past attn LDS use
    float* partial = (float*)Ks;
    u16* mv = (u16*)((char*)Ks + 1024);
    int d = tid >> 2, part = tid & 3;
    const u16* src = Vt + ((size_t)bh * HDIM + d) * LSEQ + part * 512;
    float s = 0.f;
    for (int ii = 0; ii < 512; ii += 8) {
      u16x8 v = *(const u16x8*)&src[ii];
#pragma unroll
      for (int jj = 0; jj < 8; ++jj) s += bf2f(v[jj]);
    }
    partial[tid] = s;
    __syncthreads();
    if (part == 0) {
      float t = partial[tid] + partial[tid + 1] + partial[tid + 2] + partial[tid + 3];
      mv[d] = cvt_bf(t * (1.0f / (float)LSEQ));
    }
    __syncthreads();
    int lof = lo;
    if (lof < 0) lof = 0;
    if (lof > LSEQ) lof = LSEQ;
    int total = (LSEQ - lof) * HDIM;
    for (int idx = tid; idx < total; idx += 256) {
      int row = lof + (idx >> 6), dd = idx & 63;
      Y[((size_t)b * LSEQ + row) * EMB + h * HDIM + dd] = mv[dd];
    }
  }
}

// ---------------- launch ----------------
extern "C" void kernel_launch(void* const* d_in, const int* in_sizes, int n_in,
                              void* d_out, int out_size, void* d_ws, size_t ws_size,
                              hipStream_t stream) {
  (void)in_sizes; (void)n_in; (void)out_size; (void)ws_size;
  const float* x    = (const float*)d_in[0];
  const float* Wqkv = (const float*)d_in[1];
  const float* bqkv = (const float*)d_in[2];
  const float* Wo   = (const float*)d_in[3];
  const float* bo   = (const float*)d_in[4];
  const int* mask_len = (const int*)d_in[5];
  float* out = (float*)d_out;

  u16* ws = (u16*)d_ws;
  u16* xb    = ws;                              // 4M elems (x bf16) — reused as Y later
  u16* wqkvt = ws + (size_t)4 * 1024 * 1024;    // 3M (W_qkv^T bf16)
  u16* wot   = wqkvt + (size_t)3 * 1024 * 1024; // 1M (W_o^T bf16)
  u16* Qb    = wot + (size_t)1024 * 1024;       // 4M
  u16* Kb    = Qb + (size_t)4 * 1024 * 1024;    // 4M
  u16* Vtb   = Kb + (size_t)4 * 1024 * 1024;    // 4M
  u16* Yb    = xb;                              // alias: x dead after gemm_qkv

  prep<<<4096, 256, 0, stream>>>(x, xb, Wqkv, wqkvt, Wo, wot);
  gemm_qkv<<<dim3(24, 32), 256, 0, stream>>>(xb, wqkvt, bqkv, Qb, Kb, Vtb, mask_len);
  attn_fwd<<<1024, 256, 0, stream>>>(Qb, Kb, Vtb, mask_len, Yb);
  gemm_out<<<dim3(8, 64), 256, 0, stream>>>(Yb, wot, bo, out);
}